// Round 3
// baseline (75.959 us; speedup 1.0000x reference)
//
#include <hip/hip_runtime.h>
#include <stdint.h>

// Bitnet int8 x int2 GEMM: C[M,N](i32) = A[M,K](i8) . W[N,K]^T
// Round 3: prepass writes operands in exact MFMA fragment order so all LDS
// reads are lane-linear (conflict-free). 2-phase double-buffered staging.

#define MM 1024
#define NN 11008
#define KK 4096
#define KSTEPS (KK / 64)     // 64 K-steps of 64
#define MTILES (MM / 128)    // 8
#define NTILES (NN / 128)    // 86

using i32x4  = __attribute__((ext_vector_type(4))) int;
using i32x16 = __attribute__((ext_vector_type(16))) int;

__device__ __forceinline__ int pack4(i32x4 v) {
    return (int)(((uint32_t)v[0] & 0xFFu) | (((uint32_t)v[1] & 0xFFu) << 8)
               | (((uint32_t)v[2] & 0xFFu) << 16) | (((uint32_t)v[3] & 0xFFu) << 24));
}

// A2 layout: [kstep][mtile][c]*16B where c = ((wr*2+mi)*2+kk2)*64 + lane.
// Chunk data: row = mtile*128 + wr*64 + mi*32 + (lane&31),
//             kbyte = kstep*64 + kk2*32 + (lane>>5)*16, bytes e=0..15.
__global__ __launch_bounds__(256) void prep_A(const int* __restrict__ src,
                                              uint8_t* __restrict__ dst) {
    const int g = blockIdx.x * 256 + threadIdx.x;    // < 64*8*512 = 262144
    const int kstep = g >> 12;
    const int rem   = g & 4095;
    const int mtile = rem >> 9;
    const int c     = rem & 511;
    const int wr  = (c >> 8) & 1, mi = (c >> 7) & 1, kk2 = (c >> 6) & 1;
    const int lane = c & 63;
    const int row   = mtile * 128 + wr * 64 + mi * 32 + (lane & 31);
    const int kbyte = kstep * 64 + kk2 * 32 + (lane >> 5) * 16;
    const i32x4* s4 = (const i32x4*)(src + (size_t)row * KK + kbyte);
    i32x4 o;
#pragma unroll
    for (int q = 0; q < 4; ++q) o[q] = pack4(s4[q]);
    *(i32x4*)(dst + (size_t)g * 16) = o;
}

// B2 layout: [kstep][ntile][d]*4B where d = ((wc*2+ni)*2+kk2)*64 + lane.
// Dword data: n = ntile*128 + wc*64 + ni*32 + (lane&31), j = kk2*2 + (lane>>5),
// packed from source int32 at n*(K/4) + kstep*16 + j*4 .. +3.
// Each thread produces 4 consecutive dwords (one 16B store).
__global__ __launch_bounds__(256) void prep_B(const int* __restrict__ src,
                                              uint8_t* __restrict__ dst) {
    const int t = blockIdx.x * 256 + threadIdx.x;    // < 64*86*128 = 704512
    const int kstep = t / (NTILES * 128);
    const int rem   = t % (NTILES * 128);
    const int ntile = rem >> 7;
    const int c     = rem & 127;
    const int d0    = c * 4;
    const int wc  = (d0 >> 8) & 1, ni = (d0 >> 7) & 1, kk2 = (d0 >> 6) & 1;
    const int j   = kk2 * 2 + ((d0 & 63) >> 5);
    const int n0  = ntile * 128 + wc * 64 + ni * 32 + (d0 & 31);
    i32x4 o;
#pragma unroll
    for (int q = 0; q < 4; ++q) {
        const i32x4 v = *(const i32x4*)(src + (size_t)(n0 + q) * (KK / 4) + kstep * 16 + j * 4);
        o[q] = pack4(v);
    }
    *(i32x4*)(dst + (size_t)t * 16) = o;
}

#define GLOAD_LDS16(g, l) __builtin_amdgcn_global_load_lds(                    \
        (const __attribute__((address_space(1))) uint32_t*)(g),                \
        (__attribute__((address_space(3))) uint32_t*)(l), 16, 0, 0)

// GEMM: 128x128 block tile, 4 waves 2x2, wave = 64x64 via 2x2x2
// mfma_i32_32x32x32_i8 per K-step of 64. All LDS reads lane-linear.
__global__ __launch_bounds__(256) void bitnet_gemm(const uint8_t* __restrict__ A2,
                                                   const uint8_t* __restrict__ B2,
                                                   int* __restrict__ C) {
    const int t    = threadIdx.x;
    const int lane = t & 63, wave = t >> 6;
    const int wr   = wave >> 1, wc = wave & 1;
    const int l31  = lane & 31, h = lane >> 5;
    const int by   = blockIdx.y, bx = blockIdx.x;

    __shared__ __align__(16) uint8_t As[2][8192];
    __shared__ __align__(16) uint8_t Bs[2][2048];

    i32x16 acc[2][2] = {};

    auto STAGE = [&](int buf, int ks) {
        const uint8_t* at = A2 + ((size_t)ks * MTILES + by) * 8192;
        GLOAD_LDS16(at + t * 16,        &As[buf][wave * 1024]);
        GLOAD_LDS16(at + 4096 + t * 16, &As[buf][4096 + wave * 1024]);
        if (wave < 2) {
            const uint8_t* bt = B2 + ((size_t)ks * NTILES + bx) * 2048;
            GLOAD_LDS16(bt + t * 16, &Bs[buf][wave * 1024]);
        }
    };

    auto COMPUTE = [&](int buf) {
        const uint8_t* ab = As[buf];
        const uint8_t* bb = Bs[buf];
#pragma unroll
        for (int kk2 = 0; kk2 < 2; ++kk2) {
            i32x4 a0 = *(const i32x4*)(ab + ((wr * 2 + 0) * 2 + kk2) * 1024 + lane * 16);
            i32x4 a1 = *(const i32x4*)(ab + ((wr * 2 + 1) * 2 + kk2) * 1024 + lane * 16);
            const uint32_t p0 = *(const uint32_t*)(bb + ((wc * 2 + 0) * 2 + kk2) * 256 + lane * 4);
            const uint32_t p1 = *(const uint32_t*)(bb + ((wc * 2 + 1) * 2 + kk2) * 256 + lane * 4);
            i32x4 b0, b1;
#pragma unroll
            for (int i = 0; i < 4; ++i) {
                b0[i] = (int)((p0 >> (2 * i)) & 0x03030303u);
                b1[i] = (int)((p1 >> (2 * i)) & 0x03030303u);
            }
            acc[0][0] = __builtin_amdgcn_mfma_i32_32x32x32_i8(a0, b0, acc[0][0], 0, 0, 0);
            acc[0][1] = __builtin_amdgcn_mfma_i32_32x32x32_i8(a0, b1, acc[0][1], 0, 0, 0);
            acc[1][0] = __builtin_amdgcn_mfma_i32_32x32x32_i8(a1, b0, acc[1][0], 0, 0, 0);
            acc[1][1] = __builtin_amdgcn_mfma_i32_32x32x32_i8(a1, b1, acc[1][1], 0, 0, 0);
        }
    };

    STAGE(0, 0);
    __syncthreads();

#pragma unroll 1
    for (int ks = 0; ks < KSTEPS - 2; ks += 2) {
        STAGE(1, ks + 1);
        COMPUTE(0);
        __syncthreads();
        STAGE(0, ks + 2);
        COMPUTE(1);
        __syncthreads();
    }
    STAGE(1, KSTEPS - 1);
    COMPUTE(0);
    __syncthreads();
    COMPUTE(1);

    // C write: col = lane&31, row = (r&3) + 8*(r>>2) + 4*(lane>>5)
    const int brow = by * 128, bcol = bx * 128;
#pragma unroll
    for (int mi = 0; mi < 2; ++mi)
#pragma unroll
        for (int ni = 0; ni < 2; ++ni) {
            const int colg = bcol + wc * 64 + ni * 32 + l31;
#pragma unroll
            for (int r = 0; r < 16; ++r) {
                const int rowin = (r & 3) + 8 * (r >> 2) + 4 * h;
                const int rowg  = brow + wr * 64 + mi * 32 + rowin;
                C[(size_t)rowg * NN + colg] = acc[mi][ni][r];
            }
        }
}

extern "C" void kernel_launch(void* const* d_in, const int* in_sizes, int n_in,
                              void* d_out, int out_size, void* d_ws, size_t ws_size,
                              hipStream_t stream) {
    const int* A32 = (const int*)d_in[0];   // [M,K] int8 values in int32
    const int* B32 = (const int*)d_in[1];   // [N,K/4] packed bytes in int32
    int* C = (int*)d_out;                   // [M,N] int32

    uint8_t* A2 = (uint8_t*)d_ws;                      // 4 MiB
    uint8_t* B2 = A2 + (size_t)MM * KK;                // 10.75 MiB

    prep_A<<<dim3((MM * KK / 16) / 256), dim3(256), 0, stream>>>(A32, A2);
    prep_B<<<dim3((NN * 64) / 256), dim3(256), 0, stream>>>(B32, B2);
    bitnet_gemm<<<dim3(NTILES, MTILES), dim3(256), 0, stream>>>(A2, B2, C);
}

// Round 4
// 73.531 us; speedup vs baseline: 1.0330x; 1.0330x over previous
//
#include <hip/hip_runtime.h>
#include <stdint.h>

// Bitnet int8 x int2 GEMM: C[M,N](i32) = A[M,K](i8) . W[N,K]^T
// Round 4: NO LDS, no barriers. Prepass stores operands in exact per-lane
// MFMA fragment order; GEMM loads fragments global->reg (all L2/L3-resident)
// with a 2-deep software pipeline. 128x128 block, 4 waves 2x2, wave 64x64.

#define MM 1024
#define NN 11008
#define KK 4096
#define KSTEPS 64            // K-steps of 64
#define MTILES (MM / 128)    // 8
#define NTILES (NN / 128)    // 86

using i32x4  = __attribute__((ext_vector_type(4))) int;
using i32x16 = __attribute__((ext_vector_type(16))) int;

__device__ __forceinline__ int pack4(i32x4 v) {
    return (int)(((uint32_t)v[0] & 0xFFu) | (((uint32_t)v[1] & 0xFFu) << 8)
               | (((uint32_t)v[2] & 0xFFu) << 16) | (((uint32_t)v[3] & 0xFFu) << 24));
}

// A2 layout: [kstep][mtile][slot s=(row32*2+kk2)][lane] * 16B.
// Chunk bytes: row = mtile*128 + row32*32 + (lane&31),
//              kbyte = kstep*64 + kk2*32 + (lane>>5)*16, e=0..15.
__global__ __launch_bounds__(256) void prep_A(const int* __restrict__ src,
                                              uint8_t* __restrict__ dst) {
    const int g = blockIdx.x * 256 + threadIdx.x;    // < 64*8*512 = 262144
    const int kstep = g >> 12;
    const int rem   = g & 4095;
    const int mtile = rem >> 9;
    const int c     = rem & 511;
    const int row32 = (c >> 7) & 3, kk2 = (c >> 6) & 1;
    const int lane  = c & 63;
    const int row   = mtile * 128 + row32 * 32 + (lane & 31);
    const int kbyte = kstep * 64 + kk2 * 32 + (lane >> 5) * 16;
    const i32x4* s4 = (const i32x4*)(src + (size_t)row * KK + kbyte);
    i32x4 o;
#pragma unroll
    for (int q = 0; q < 4; ++q) o[q] = pack4(s4[q]);
    *(i32x4*)(dst + (size_t)g * 16) = o;
}

// B3 layout: [kstep][ntile][wc][lane] * 16B; the 4 dwords (q = ni*2+kk2) a
// lane needs per K-step are contiguous. Dword (q): packed bytes of row
// n = ntile*128 + wc*64 + ni*32 + (lane&31) at int32 offset
// kstep*16 + kk2*8 + (lane>>5)*4 .. +3.
__global__ __launch_bounds__(256) void prep_B(const int* __restrict__ src,
                                              uint8_t* __restrict__ dst) {
    const int t = blockIdx.x * 256 + threadIdx.x;    // < 64*86*128 = 704512
    const int lane = t & 63;
    const int wc   = (t >> 6) & 1;
    const int rem  = t >> 7;            // kstep*NTILES + ntile
    const int ntile = rem % NTILES;
    const int kstep = rem / NTILES;
    const int l31 = lane & 31, h = lane >> 5;
    i32x4 o;
#pragma unroll
    for (int q = 0; q < 4; ++q) {
        const int ni = q >> 1, kk2 = q & 1;
        const int n  = ntile * 128 + wc * 64 + ni * 32 + l31;
        const i32x4 v = *(const i32x4*)(src + (size_t)n * (KK / 4) + kstep * 16 + kk2 * 8 + h * 4);
        o[q] = pack4(v);
    }
    *(i32x4*)(dst + (size_t)t * 16) = o;
}

// GEMM: no LDS. Each wave: 64x64 output (2x2 MFMA tiles), fragments loaded
// lane-linear from A2/B3, 2-deep rotating prefetch, no synchronization.
__global__ __launch_bounds__(256, 3) void bitnet_gemm(const uint8_t* __restrict__ A2,
                                                      const uint8_t* __restrict__ B3,
                                                      int* __restrict__ C) {
    const int t    = threadIdx.x;
    const int lane = t & 63, wave = t >> 6;
    const int wr   = wave >> 1, wc = wave & 1;
    const int l31  = lane & 31, h = lane >> 5;
    const int by   = blockIdx.y, bx = blockIdx.x;

    const size_t strideA = (size_t)MTILES * 8192;   // A2 bytes per kstep
    const size_t strideB = (size_t)NTILES * 2048;   // B3 bytes per kstep

    const uint8_t* pa[4];   // s = mi*2 + kk2
#pragma unroll
    for (int s = 0; s < 4; ++s) {
        const int mi = s >> 1, kk2 = s & 1;
        pa[s] = A2 + (size_t)by * 8192 + ((wr * 2 + mi) * 2 + kk2) * 1024 + lane * 16;
    }
    const uint8_t* pb = B3 + (size_t)bx * 2048 + wc * 1024 + lane * 16;

    i32x16 acc[2][2] = {};
    i32x4 a0[4], a1[4], p0, p1;

    auto LOAD = [&](i32x4 (&a)[4], i32x4& p, int ks) {
#pragma unroll
        for (int s = 0; s < 4; ++s)
            a[s] = *(const i32x4*)(pa[s] + (size_t)ks * strideA);
        p = *(const i32x4*)(pb + (size_t)ks * strideB);
    };

    auto COMPUTE = [&](const i32x4 (&a)[4], const i32x4& p) {
#pragma unroll
        for (int kk2 = 0; kk2 < 2; ++kk2) {
            const uint32_t q0 = (uint32_t)p[kk2];        // ni = 0
            const uint32_t q1 = (uint32_t)p[2 + kk2];    // ni = 1
            i32x4 b0, b1;
#pragma unroll
            for (int i = 0; i < 4; ++i) {
                b0[i] = (int)((q0 >> (2 * i)) & 0x03030303u);
                b1[i] = (int)((q1 >> (2 * i)) & 0x03030303u);
            }
            acc[0][0] = __builtin_amdgcn_mfma_i32_32x32x32_i8(a[0 * 2 + kk2], b0, acc[0][0], 0, 0, 0);
            acc[0][1] = __builtin_amdgcn_mfma_i32_32x32x32_i8(a[0 * 2 + kk2], b1, acc[0][1], 0, 0, 0);
            acc[1][0] = __builtin_amdgcn_mfma_i32_32x32x32_i8(a[1 * 2 + kk2], b0, acc[1][0], 0, 0, 0);
            acc[1][1] = __builtin_amdgcn_mfma_i32_32x32x32_i8(a[1 * 2 + kk2], b1, acc[1][1], 0, 0, 0);
        }
    };

    LOAD(a0, p0, 0);
    LOAD(a1, p1, 1);

#pragma unroll 1
    for (int ks = 0; ks < KSTEPS - 2; ks += 2) {
        COMPUTE(a0, p0);
        LOAD(a0, p0, ks + 2);
        COMPUTE(a1, p1);
        LOAD(a1, p1, ks + 3);
    }
    COMPUTE(a0, p0);
    COMPUTE(a1, p1);

    // C write: col = lane&31, row = (r&3) + 8*(r>>2) + 4*(lane>>5)
    const int brow = by * 128, bcol = bx * 128;
#pragma unroll
    for (int mi = 0; mi < 2; ++mi)
#pragma unroll
        for (int ni = 0; ni < 2; ++ni) {
            const int colg = bcol + wc * 64 + ni * 32 + l31;
#pragma unroll
            for (int r = 0; r < 16; ++r) {
                const int rowin = (r & 3) + 8 * (r >> 2) + 4 * h;
                const int rowg  = brow + wr * 64 + mi * 32 + rowin;
                C[(size_t)rowg * NN + colg] = acc[mi][ni][r];
            }
        }
}

extern "C" void kernel_launch(void* const* d_in, const int* in_sizes, int n_in,
                              void* d_out, int out_size, void* d_ws, size_t ws_size,
                              hipStream_t stream) {
    const int* A32 = (const int*)d_in[0];   // [M,K] int8 values in int32
    const int* B32 = (const int*)d_in[1];   // [N,K/4] packed bytes in int32
    int* C = (int*)d_out;                   // [M,N] int32

    uint8_t* A2 = (uint8_t*)d_ws;                      // 4 MiB
    uint8_t* B3 = A2 + (size_t)MM * KK;                // 10.75 MiB

    prep_A<<<dim3((MM * KK / 16) / 256), dim3(256), 0, stream>>>(A32, A2);
    prep_B<<<dim3((NN * 64) / 256), dim3(256), 0, stream>>>(B32, B3);
    bitnet_gemm<<<dim3(NTILES, MTILES), dim3(256), 0, stream>>>(A2, B3, C);
}

// Round 5
// 73.138 us; speedup vs baseline: 1.0386x; 1.0054x over previous
//
#include <hip/hip_runtime.h>
#include <stdint.h>

// Bitnet int8 x int2 GEMM: C[M,N](i32) = A[M,K](i8) . W[N,K]^T
// Round 5: no-LDS fragment-direct kernel with 4-deep software pipeline
// (load->use distance ~550 cyc to cover contended L2 latency).

#define MM 1024
#define NN 11008
#define KK 4096
#define KSTEPS 64            // K-steps of 64
#define MTILES (MM / 128)    // 8
#define NTILES (NN / 128)    // 86

using i32x4  = __attribute__((ext_vector_type(4))) int;
using i32x16 = __attribute__((ext_vector_type(16))) int;

__device__ __forceinline__ int pack4(i32x4 v) {
    return (int)(((uint32_t)v[0] & 0xFFu) | (((uint32_t)v[1] & 0xFFu) << 8)
               | (((uint32_t)v[2] & 0xFFu) << 16) | (((uint32_t)v[3] & 0xFFu) << 24));
}

// A2 layout: [kstep][mtile][slot s=(row32*2+kk2)][lane] * 16B.
// Chunk bytes: row = mtile*128 + row32*32 + (lane&31),
//              kbyte = kstep*64 + kk2*32 + (lane>>5)*16, e=0..15.
__global__ __launch_bounds__(256) void prep_A(const int* __restrict__ src,
                                              uint8_t* __restrict__ dst) {
    const int g = blockIdx.x * 256 + threadIdx.x;    // < 64*8*512 = 262144
    const int kstep = g >> 12;
    const int rem   = g & 4095;
    const int mtile = rem >> 9;
    const int c     = rem & 511;
    const int row32 = (c >> 7) & 3, kk2 = (c >> 6) & 1;
    const int lane  = c & 63;
    const int row   = mtile * 128 + row32 * 32 + (lane & 31);
    const int kbyte = kstep * 64 + kk2 * 32 + (lane >> 5) * 16;
    const i32x4* s4 = (const i32x4*)(src + (size_t)row * KK + kbyte);
    i32x4 o;
#pragma unroll
    for (int q = 0; q < 4; ++q) o[q] = pack4(s4[q]);
    *(i32x4*)(dst + (size_t)g * 16) = o;
}

// B3 layout: [kstep][ntile][wc][lane] * 16B; the 4 dwords (q = ni*2+kk2) a
// lane needs per K-step are contiguous. Dword (q): packed bytes of row
// n = ntile*128 + wc*64 + ni*32 + (lane&31) at int32 offset
// kstep*16 + kk2*8 + (lane>>5)*4 .. +3.
__global__ __launch_bounds__(256) void prep_B(const int* __restrict__ src,
                                              uint8_t* __restrict__ dst) {
    const int t = blockIdx.x * 256 + threadIdx.x;    // < 64*86*128 = 704512
    const int lane = t & 63;
    const int wc   = (t >> 6) & 1;
    const int rem  = t >> 7;            // kstep*NTILES + ntile
    const int ntile = rem % NTILES;
    const int kstep = rem / NTILES;
    const int l31 = lane & 31, h = lane >> 5;
    i32x4 o;
#pragma unroll
    for (int q = 0; q < 4; ++q) {
        const int ni = q >> 1, kk2 = q & 1;
        const int n  = ntile * 128 + wc * 64 + ni * 32 + l31;
        const i32x4 v = *(const i32x4*)(src + (size_t)n * (KK / 4) + kstep * 16 + kk2 * 8 + h * 4);
        o[q] = pack4(v);
    }
    *(i32x4*)(dst + (size_t)t * 16) = o;
}

// GEMM: no LDS, no barriers. Wave = 64x64 (2x2 MFMA tiles), fragments loaded
// lane-linear from A2/B3. 4-deep rotating register prefetch (static indices).
__global__ __launch_bounds__(256, 3) void bitnet_gemm(const uint8_t* __restrict__ A2,
                                                      const uint8_t* __restrict__ B3,
                                                      int* __restrict__ C) {
    const int t    = threadIdx.x;
    const int lane = t & 63, wave = t >> 6;
    const int wr   = wave >> 1, wc = wave & 1;
    const int l31  = lane & 31, h = lane >> 5;
    const int by   = blockIdx.y, bx = blockIdx.x;

    const size_t strideA = (size_t)MTILES * 8192;   // A2 bytes per kstep
    const size_t strideB = (size_t)NTILES * 2048;   // B3 bytes per kstep

    const uint8_t* pa[4];   // s = mi*2 + kk2
#pragma unroll
    for (int s = 0; s < 4; ++s) {
        const int mi = s >> 1, kk2 = s & 1;
        pa[s] = A2 + (size_t)by * 8192 + ((wr * 2 + mi) * 2 + kk2) * 1024 + lane * 16;
    }
    const uint8_t* pb = B3 + (size_t)bx * 2048 + wc * 1024 + lane * 16;

    i32x16 acc[2][2] = {};
    i32x4 fa0[4], fa1[4], fa2[4], fa3[4];
    i32x4 fp0, fp1, fp2, fp3;

    auto LOAD = [&](i32x4 (&a)[4], i32x4& p, int ks) {
#pragma unroll
        for (int s = 0; s < 4; ++s)
            a[s] = *(const i32x4*)(pa[s] + (size_t)ks * strideA);
        p = *(const i32x4*)(pb + (size_t)ks * strideB);
    };

    auto COMPUTE = [&](const i32x4 (&a)[4], const i32x4& p) {
#pragma unroll
        for (int kk2 = 0; kk2 < 2; ++kk2) {
            const uint32_t q0 = (uint32_t)p[kk2];        // ni = 0
            const uint32_t q1 = (uint32_t)p[2 + kk2];    // ni = 1
            i32x4 b0, b1;
#pragma unroll
            for (int i = 0; i < 4; ++i) {
                b0[i] = (int)((q0 >> (2 * i)) & 0x03030303u);
                b1[i] = (int)((q1 >> (2 * i)) & 0x03030303u);
            }
            acc[0][0] = __builtin_amdgcn_mfma_i32_32x32x32_i8(a[0 * 2 + kk2], b0, acc[0][0], 0, 0, 0);
            acc[0][1] = __builtin_amdgcn_mfma_i32_32x32x32_i8(a[0 * 2 + kk2], b1, acc[0][1], 0, 0, 0);
            acc[1][0] = __builtin_amdgcn_mfma_i32_32x32x32_i8(a[1 * 2 + kk2], b0, acc[1][0], 0, 0, 0);
            acc[1][1] = __builtin_amdgcn_mfma_i32_32x32x32_i8(a[1 * 2 + kk2], b1, acc[1][1], 0, 0, 0);
        }
    };

    LOAD(fa0, fp0, 0);
    LOAD(fa1, fp1, 1);
    LOAD(fa2, fp2, 2);
    LOAD(fa3, fp3, 3);

#pragma unroll 1
    for (int ks = 0; ks < KSTEPS - 4; ks += 4) {
        COMPUTE(fa0, fp0); LOAD(fa0, fp0, ks + 4);
        COMPUTE(fa1, fp1); LOAD(fa1, fp1, ks + 5);
        COMPUTE(fa2, fp2); LOAD(fa2, fp2, ks + 6);
        COMPUTE(fa3, fp3); LOAD(fa3, fp3, ks + 7);
    }
    COMPUTE(fa0, fp0);
    COMPUTE(fa1, fp1);
    COMPUTE(fa2, fp2);
    COMPUTE(fa3, fp3);

    // C write: col = lane&31, row = (r&3) + 8*(r>>2) + 4*(lane>>5)
    const int brow = by * 128, bcol = bx * 128;
#pragma unroll
    for (int mi = 0; mi < 2; ++mi)
#pragma unroll
        for (int ni = 0; ni < 2; ++ni) {
            const int colg = bcol + wc * 64 + ni * 32 + l31;
#pragma unroll
            for (int r = 0; r < 16; ++r) {
                const int rowin = (r & 3) + 8 * (r >> 2) + 4 * h;
                const int rowg  = brow + wr * 64 + mi * 32 + rowin;
                C[(size_t)rowg * NN + colg] = acc[mi][ni][r];
            }
        }
}

extern "C" void kernel_launch(void* const* d_in, const int* in_sizes, int n_in,
                              void* d_out, int out_size, void* d_ws, size_t ws_size,
                              hipStream_t stream) {
    const int* A32 = (const int*)d_in[0];   // [M,K] int8 values in int32
    const int* B32 = (const int*)d_in[1];   // [N,K/4] packed bytes in int32
    int* C = (int*)d_out;                   // [M,N] int32

    uint8_t* A2 = (uint8_t*)d_ws;                      // 4 MiB
    uint8_t* B3 = A2 + (size_t)MM * KK;                // 10.75 MiB

    prep_A<<<dim3((MM * KK / 16) / 256), dim3(256), 0, stream>>>(A32, A2);
    prep_B<<<dim3((NN * 64) / 256), dim3(256), 0, stream>>>(B32, B3);
    bitnet_gemm<<<dim3(NTILES, MTILES), dim3(256), 0, stream>>>(A2, B3, C);
}

// Round 6
// 69.841 us; speedup vs baseline: 1.0876x; 1.0472x over previous
//
#include <hip/hip_runtime.h>
#include <stdint.h>

// Bitnet int8 x int2 GEMM: C[M,N](i32) = A[M,K](i8) . W[N,K]^T
// Round 6: no-LDS, single-wave blocks. Wave tile 64x128 (2x4 MFMA tiles,
// 128 AGPR acc) halves fragment bytes per MFMA (0.625 -> 0.375 KB/MFMA).
// 1376 one-wave blocks, XCD-chunked swizzle, 2-deep register pipeline.

#define MM 1024
#define NN 11008
#define KK 4096
#define KSTEPS 64            // K-steps of 64
#define MTILES (MM / 128)    // 8   (A2 layout granule is 128 rows)
#define NTILES (NN / 128)    // 86
#define NWAVES (16 * NTILES) // 1376 = (M/64) * (N/128)

using i32x4  = __attribute__((ext_vector_type(4))) int;
using i32x16 = __attribute__((ext_vector_type(16))) int;

__device__ __forceinline__ int pack4(i32x4 v) {
    return (int)(((uint32_t)v[0] & 0xFFu) | (((uint32_t)v[1] & 0xFFu) << 8)
               | (((uint32_t)v[2] & 0xFFu) << 16) | (((uint32_t)v[3] & 0xFFu) << 24));
}

// A2 layout: [kstep][mtile][slot s=(row32*2+kk2)][lane] * 16B.
// Chunk bytes: row = mtile*128 + row32*32 + (lane&31),
//              kbyte = kstep*64 + kk2*32 + (lane>>5)*16, e=0..15.
__global__ __launch_bounds__(256) void prep_A(const int* __restrict__ src,
                                              uint8_t* __restrict__ dst) {
    const int g = blockIdx.x * 256 + threadIdx.x;    // < 64*8*512 = 262144
    const int kstep = g >> 12;
    const int rem   = g & 4095;
    const int mtile = rem >> 9;
    const int c     = rem & 511;
    const int row32 = (c >> 7) & 3, kk2 = (c >> 6) & 1;
    const int lane  = c & 63;
    const int row   = mtile * 128 + row32 * 32 + (lane & 31);
    const int kbyte = kstep * 64 + kk2 * 32 + (lane >> 5) * 16;
    const i32x4* s4 = (const i32x4*)(src + (size_t)row * KK + kbyte);
    i32x4 o;
#pragma unroll
    for (int q = 0; q < 4; ++q) o[q] = pack4(s4[q]);
    *(i32x4*)(dst + (size_t)g * 16) = o;
}

// B3 layout: [kstep][ntile][wc][lane] * 16B; dword q = ni*2+kk2 holds packed
// bytes of row n = ntile*128 + wc*64 + ni*32 + (lane&31) at int32 offset
// kstep*16 + kk2*8 + (lane>>5)*4 .. +3.
__global__ __launch_bounds__(256) void prep_B(const int* __restrict__ src,
                                              uint8_t* __restrict__ dst) {
    const int t = blockIdx.x * 256 + threadIdx.x;    // < 64*86*128 = 704512
    const int lane = t & 63;
    const int wc   = (t >> 6) & 1;
    const int rem  = t >> 7;            // kstep*NTILES + ntile
    const int ntile = rem % NTILES;
    const int kstep = rem / NTILES;
    const int l31 = lane & 31, h = lane >> 5;
    i32x4 o;
#pragma unroll
    for (int q = 0; q < 4; ++q) {
        const int ni = q >> 1, kk2 = q & 1;
        const int n  = ntile * 128 + wc * 64 + ni * 32 + l31;
        const i32x4 v = *(const i32x4*)(src + (size_t)n * (KK / 4) + kstep * 16 + kk2 * 8 + h * 4);
        o[q] = pack4(v);
    }
    *(i32x4*)(dst + (size_t)t * 16) = o;
}

struct Bfrag { i32x4 c0, c1; };   // the two 16B B-chunks (cols 0-63, 64-127)

// GEMM: one wave per block, 64x128 output tile (mi 0..1, nc 0..3), no LDS.
__global__ __launch_bounds__(64, 2) void bitnet_gemm(const uint8_t* __restrict__ A2,
                                                     const uint8_t* __restrict__ B3,
                                                     int* __restrict__ C) {
    const int lane = threadIdx.x;
    const int l31  = lane & 31, h = lane >> 5;

    // bijective XCD swizzle (NWAVES % 8 == 0): each XCD gets a contiguous
    // logical chunk; wm fastest so same-wn waves co-reside (B L2-broadcast).
    const int bid = blockIdx.x;
    const int l   = (bid & 7) * (NWAVES / 8) + (bid >> 3);
    const int wm  = l & 15;      // 64-row strip 0..15
    const int wn  = l >> 4;      // 128-col tile 0..85
    const int mtile = wm >> 1, half = wm & 1;

    const size_t strideA = (size_t)MTILES * 8192;
    const size_t strideB = (size_t)NTILES * 2048;

    const uint8_t* pa[4];   // s = mi*2 + kk2
#pragma unroll
    for (int s = 0; s < 4; ++s) {
        const int mi = s >> 1, kk2 = s & 1;
        pa[s] = A2 + (size_t)mtile * 8192 + ((half * 2 + mi) * 2 + kk2) * 1024 + lane * 16;
    }
    const uint8_t* pb = B3 + (size_t)wn * 2048 + lane * 16;

    i32x16 acc[2][4] = {};
    i32x4 fa0[4], fa1[4];
    Bfrag fp0, fp1;

    auto LOAD = [&](i32x4 (&a)[4], Bfrag& p, int ks) {
#pragma unroll
        for (int s = 0; s < 4; ++s)
            a[s] = *(const i32x4*)(pa[s] + (size_t)ks * strideA);
        p.c0 = *(const i32x4*)(pb + (size_t)ks * strideB);
        p.c1 = *(const i32x4*)(pb + (size_t)ks * strideB + 1024);
    };

    auto COMPUTE = [&](const i32x4 (&a)[4], const Bfrag& p) {
#pragma unroll
        for (int kk2 = 0; kk2 < 2; ++kk2) {
#pragma unroll
            for (int nc = 0; nc < 4; ++nc) {
                const uint32_t q = (uint32_t)((nc < 2 ? p.c0 : p.c1)[(nc & 1) * 2 + kk2]);
                i32x4 b;
#pragma unroll
                for (int i = 0; i < 4; ++i)
                    b[i] = (int)((q >> (2 * i)) & 0x03030303u);
                acc[0][nc] = __builtin_amdgcn_mfma_i32_32x32x32_i8(a[0 + kk2], b, acc[0][nc], 0, 0, 0);
                acc[1][nc] = __builtin_amdgcn_mfma_i32_32x32x32_i8(a[2 + kk2], b, acc[1][nc], 0, 0, 0);
            }
        }
    };

    LOAD(fa0, fp0, 0);
    LOAD(fa1, fp1, 1);

#pragma unroll 1
    for (int ks = 0; ks < KSTEPS - 2; ks += 2) {
        COMPUTE(fa0, fp0); LOAD(fa0, fp0, ks + 2);
        COMPUTE(fa1, fp1); LOAD(fa1, fp1, ks + 3);
    }
    COMPUTE(fa0, fp0);
    COMPUTE(fa1, fp1);

    // C write: col = lane&31, row = (r&3) + 8*(r>>2) + 4*(lane>>5)
    const int brow = wm * 64, bcol = wn * 128;
#pragma unroll
    for (int mi = 0; mi < 2; ++mi)
#pragma unroll
        for (int nc = 0; nc < 4; ++nc) {
            const int colg = bcol + nc * 32 + l31;
#pragma unroll
            for (int r = 0; r < 16; ++r) {
                const int rowin = (r & 3) + 8 * (r >> 2) + 4 * h;
                const int rowg  = brow + mi * 32 + rowin;
                C[(size_t)rowg * NN + colg] = acc[mi][nc][r];
            }
        }
}

extern "C" void kernel_launch(void* const* d_in, const int* in_sizes, int n_in,
                              void* d_out, int out_size, void* d_ws, size_t ws_size,
                              hipStream_t stream) {
    const int* A32 = (const int*)d_in[0];   // [M,K] int8 values in int32
    const int* B32 = (const int*)d_in[1];   // [N,K/4] packed bytes in int32
    int* C = (int*)d_out;                   // [M,N] int32

    uint8_t* A2 = (uint8_t*)d_ws;                      // 4 MiB
    uint8_t* B3 = A2 + (size_t)MM * KK;                // 10.75 MiB

    prep_A<<<dim3((MM * KK / 16) / 256), dim3(256), 0, stream>>>(A32, A2);
    prep_B<<<dim3((NN * 64) / 256), dim3(256), 0, stream>>>(B32, B3);
    bitnet_gemm<<<dim3(NWAVES), dim3(64), 0, stream>>>(A2, B3, C);
}